// Round 21
// baseline (353.530 us; speedup 1.0000x reference)
//
#include <hip/hip_runtime.h>
#include <hip/hip_bf16.h>
#include <math.h>

#define G_   64      // B*T graphs
#define NN_  500     // nodes
#define FIN_ 32
#define HD_  128
#define C1_  256     // HEADS*HD
#define E0_  8000
#define EP_  8500    // E0 + self loops
#define TT_  16
#define NR_  2000    // B*N lstm rows

typedef __attribute__((ext_vector_type(8))) short bf16x8;
typedef __attribute__((ext_vector_type(4))) float f32x4;

__device__ __forceinline__ float fsig(float x)  { return 1.f / (1.f + __expf(-x)); }
__device__ __forceinline__ float ftanh(float x) {
    float e = __expf(fminf(fmaxf(2.f * x, -30.f), 30.f));
    return (e - 1.f) / (e + 1.f);
}
__device__ __forceinline__ unsigned short f2bf(float f) {
    unsigned int u = __float_as_uint(f);
    return (unsigned short)((u + 0x7FFFu + ((u >> 16) & 1u)) >> 16);
}
__device__ __forceinline__ float bf2f(unsigned short h) {
    return __uint_as_float(((unsigned int)h) << 16);
}

// ---------------- CSR build (by dst): fused degree+scan, then fill ----------------
__global__ __launch_bounds__(512) void k_degscan(const int* __restrict__ ei,
                                                 int* __restrict__ rowptr, int* __restrict__ cursor) {
    __shared__ int degs[512];
    __shared__ int scan[512];
    int t = threadIdx.x;
    degs[t] = 0;
    __syncthreads();
    for (int e = t; e < EP_; e += 512) {
        int dst = e < E0_ ? ei[E0_ + e] : e - E0_;
        atomicAdd(&degs[dst], 1);
    }
    __syncthreads();
    int v = degs[t];
    scan[t] = v;
    __syncthreads();
    for (int off = 1; off < 512; off <<= 1) {
        int add = (t >= off) ? scan[t - off] : 0;
        __syncthreads();
        scan[t] += add;
        __syncthreads();
    }
    int ex = scan[t] - v;   // exclusive prefix
    if (t < NN_) { rowptr[t] = ex; cursor[t] = ex; }
    if (t == NN_) rowptr[NN_] = ex;
}
__global__ void k_fill(const int* __restrict__ ei, int* __restrict__ cursor, int* __restrict__ eids) {
    int e = blockIdx.x * blockDim.x + threadIdx.x;
    if (e >= EP_) return;
    int dst = e < E0_ ? ei[E0_ + e] : e - E0_;
    int pos = atomicAdd(&cursor[dst], 1);
    eids[pos] = e;
}

// ---------------- LSTM weight prepack: bf16-hi only ----------------
__global__ void k_wt(const float* __restrict__ Whh0, const float* __restrict__ Wih0,
                     const float* __restrict__ Whh1, const float* __restrict__ Wih1,
                     unsigned short* __restrict__ WB0, unsigned short* __restrict__ WB1) {
    int layer = blockIdx.y;
    int n = blockIdx.x * 256 + threadIdx.x;   // 0..131071
    const float* Wh = layer ? Whh1 : Whh0;
    const float* Wi = layer ? Wih1 : Wih0;
    unsigned short* WB = layer ? WB1 : WB0;
    int j = n & 7, col = (n >> 3) & 511, kb8 = n >> 12;
    int k = kb8 * 8 + j;
    float w = (k < 128) ? Wh[(size_t)col * 128 + k] : Wi[(size_t)col * 128 + (k - 128)];
    WB[n] = f2bf(w);
}

// ---------------- GAT weight prepack: 5 matrices -> hi/lo B-fragments ----------------
__global__ void k_wtg(const float* __restrict__ Wl1, const float* __restrict__ Wr1,
                      const float* __restrict__ Wp,  const float* __restrict__ W2l,
                      const float* __restrict__ W2r, unsigned short* __restrict__ out) {
    int t = blockIdx.x * 256 + threadIdx.x;
    if (t >= 86016) return;
    const float* W; int N, base, local, KN;
    if (t < 8192)       { W = Wl1; N = 256; base = 0;      local = t;         KN = 8192;  }
    else if (t < 16384) { W = Wr1; N = 256; base = 16384;  local = t - 8192;  KN = 8192;  }
    else if (t < 20480) { W = Wp;  N = 128; base = 32768;  local = t - 16384; KN = 4096;  }
    else if (t < 53248) { W = W2l; N = 128; base = 40960;  local = t - 20480; KN = 32768; }
    else                { W = W2r; N = 128; base = 106496; local = t - 53248; KN = 32768; }
    int k = local / N, n = local - k * N;
    float wv = W[local];
    int idx = ((k >> 3) * N + n) * 8 + (k & 7);
    unsigned short h = f2bf(wv);
    out[base + idx] = h;
    out[base + KN + idx] = f2bf(wv - bf2f(h));
}

// ---------------- MFMA GEMM 1: x[32000,32] @ {Wl,Wr,Wp} -> xl1, xr1, proj ----------------
__global__ __launch_bounds__(256) void k_mm1(
    const float* __restrict__ x, const unsigned short* __restrict__ WP,
    const float* __restrict__ bp,
    float* __restrict__ xl1, float* __restrict__ xr1, float* __restrict__ proj)
{
    int tid = threadIdx.x, lane = tid & 63, w = tid >> 6;
    int row = lane & 15, kg = lane >> 4;
    int rb = blockIdx.x * 64 + w * 16;
    const float* ap = &x[(size_t)(rb + row) * 32 + kg * 8];
    float4 a0 = *(const float4*)ap, a1 = *(const float4*)(ap + 4);
    union { unsigned short u[8]; bf16x8 v; } ah, al;
    {
        float av[8] = {a0.x,a0.y,a0.z,a0.w,a1.x,a1.y,a1.z,a1.w};
        #pragma unroll
        for (int j = 0; j < 8; ++j) {
            unsigned short hb = f2bf(av[j]);
            ah.u[j] = hb;
            al.u[j] = f2bf(av[j] - bf2f(hb));
        }
    }
    const int crow = kg * 4;
    #pragma unroll 4
    for (int nt = 0; nt < 16; ++nt) {
        int n = nt * 16 + row;
        int idx = (kg * 256 + n) * 8;
        bf16x8 bh = *(const bf16x8*)(WP + idx);
        bf16x8 bl = *(const bf16x8*)(WP + 8192 + idx);
        f32x4 acc = {0.f,0.f,0.f,0.f};
        acc = __builtin_amdgcn_mfma_f32_16x16x32_bf16(ah.v, bh, acc, 0, 0, 0);
        acc = __builtin_amdgcn_mfma_f32_16x16x32_bf16(al.v, bh, acc, 0, 0, 0);
        acc = __builtin_amdgcn_mfma_f32_16x16x32_bf16(ah.v, bl, acc, 0, 0, 0);
        #pragma unroll
        for (int r = 0; r < 4; ++r)
            xl1[(size_t)(rb + crow + r) * 256 + n] = acc[r];
    }
    #pragma unroll 4
    for (int nt = 0; nt < 16; ++nt) {
        int n = nt * 16 + row;
        int idx = (kg * 256 + n) * 8;
        bf16x8 bh = *(const bf16x8*)(WP + 16384 + idx);
        bf16x8 bl = *(const bf16x8*)(WP + 24576 + idx);
        f32x4 acc = {0.f,0.f,0.f,0.f};
        acc = __builtin_amdgcn_mfma_f32_16x16x32_bf16(ah.v, bh, acc, 0, 0, 0);
        acc = __builtin_amdgcn_mfma_f32_16x16x32_bf16(al.v, bh, acc, 0, 0, 0);
        acc = __builtin_amdgcn_mfma_f32_16x16x32_bf16(ah.v, bl, acc, 0, 0, 0);
        #pragma unroll
        for (int r = 0; r < 4; ++r)
            xr1[(size_t)(rb + crow + r) * 256 + n] = acc[r];
    }
    #pragma unroll 4
    for (int nt = 0; nt < 8; ++nt) {
        int n = nt * 16 + row;
        int idx = (kg * 128 + n) * 8;
        bf16x8 bh = *(const bf16x8*)(WP + 32768 + idx);
        bf16x8 bl = *(const bf16x8*)(WP + 36864 + idx);
        f32x4 acc = {0.f,0.f,0.f,0.f};
        acc = __builtin_amdgcn_mfma_f32_16x16x32_bf16(ah.v, bh, acc, 0, 0, 0);
        acc = __builtin_amdgcn_mfma_f32_16x16x32_bf16(al.v, bh, acc, 0, 0, 0);
        acc = __builtin_amdgcn_mfma_f32_16x16x32_bf16(ah.v, bl, acc, 0, 0, 0);
        float bv = bp[n];
        #pragma unroll
        for (int r = 0; r < 4; ++r)
            proj[(size_t)(rb + crow + r) * 128 + n] = acc[r] + bv;
    }
}

// ---------------- MFMA GEMM 2: elu(bn(h1)) @ {W2l,W2r} -> xl2, xr2 ----------------
__global__ __launch_bounds__(512) void k_mm2(
    const float* __restrict__ h1, const unsigned short* __restrict__ WP,
    const float* __restrict__ sc1, const float* __restrict__ sh1,
    float* __restrict__ xl2, float* __restrict__ xr2)
{
    int tid = threadIdx.x, lane = tid & 63, w = tid >> 6;
    int wr = w >> 2, wc = w & 3;
    int row = lane & 15, kg = lane >> 4;
    int rb = blockIdx.x * 32 + wr * 16;
    int grow = rb + row;
    int g = grow / NN_;
    const float* scp = sc1 + g * 256;
    const float* shp = sh1 + g * 256;
    const int cb = wc * 32 + row;
    f32x4 aL0 = {0.f,0.f,0.f,0.f}, aL1 = {0.f,0.f,0.f,0.f};
    f32x4 aR0 = {0.f,0.f,0.f,0.f}, aR1 = {0.f,0.f,0.f,0.f};
    #pragma unroll 2
    for (int kt = 0; kt < 8; ++kt) {
        int k0 = kt * 32 + kg * 8;
        const float* hp = &h1[(size_t)grow * 256 + k0];
        float4 h0 = *(const float4*)hp, h4 = *(const float4*)(hp + 4);
        float4 s0 = *(const float4*)&scp[k0], s4 = *(const float4*)&scp[k0 + 4];
        float4 t0 = *(const float4*)&shp[k0], t4 = *(const float4*)&shp[k0 + 4];
        union { unsigned short u[8]; bf16x8 v; } ah, al;
        {
            float hv[8] = {h0.x,h0.y,h0.z,h0.w,h4.x,h4.y,h4.z,h4.w};
            float sv[8] = {s0.x,s0.y,s0.z,s0.w,s4.x,s4.y,s4.z,s4.w};
            float tv[8] = {t0.x,t0.y,t0.z,t0.w,t4.x,t4.y,t4.z,t4.w};
            #pragma unroll
            for (int j = 0; j < 8; ++j) {
                float v = hv[j] * sv[j] + tv[j];
                v = v > 0.f ? v : expm1f(v);
                unsigned short hb = f2bf(v);
                ah.u[j] = hb;
                al.u[j] = f2bf(v - bf2f(hb));
            }
        }
        int idx = ((kt * 4 + kg) * 128 + cb) * 8;
        bf16x8 bhL0 = *(const bf16x8*)(WP + 40960 + idx);
        bf16x8 blL0 = *(const bf16x8*)(WP + 73728 + idx);
        bf16x8 bhL1 = *(const bf16x8*)(WP + 40960 + idx + 128);
        bf16x8 blL1 = *(const bf16x8*)(WP + 73728 + idx + 128);
        bf16x8 bhR0 = *(const bf16x8*)(WP + 106496 + idx);
        bf16x8 blR0 = *(const bf16x8*)(WP + 139264 + idx);
        bf16x8 bhR1 = *(const bf16x8*)(WP + 106496 + idx + 128);
        bf16x8 blR1 = *(const bf16x8*)(WP + 139264 + idx + 128);
        aL0 = __builtin_amdgcn_mfma_f32_16x16x32_bf16(ah.v, bhL0, aL0, 0, 0, 0);
        aL0 = __builtin_amdgcn_mfma_f32_16x16x32_bf16(al.v, bhL0, aL0, 0, 0, 0);
        aL0 = __builtin_amdgcn_mfma_f32_16x16x32_bf16(ah.v, blL0, aL0, 0, 0, 0);
        aL1 = __builtin_amdgcn_mfma_f32_16x16x32_bf16(ah.v, bhL1, aL1, 0, 0, 0);
        aL1 = __builtin_amdgcn_mfma_f32_16x16x32_bf16(al.v, bhL1, aL1, 0, 0, 0);
        aL1 = __builtin_amdgcn_mfma_f32_16x16x32_bf16(ah.v, blL1, aL1, 0, 0, 0);
        aR0 = __builtin_amdgcn_mfma_f32_16x16x32_bf16(ah.v, bhR0, aR0, 0, 0, 0);
        aR0 = __builtin_amdgcn_mfma_f32_16x16x32_bf16(al.v, bhR0, aR0, 0, 0, 0);
        aR0 = __builtin_amdgcn_mfma_f32_16x16x32_bf16(ah.v, blR0, aR0, 0, 0, 0);
        aR1 = __builtin_amdgcn_mfma_f32_16x16x32_bf16(ah.v, bhR1, aR1, 0, 0, 0);
        aR1 = __builtin_amdgcn_mfma_f32_16x16x32_bf16(al.v, bhR1, aR1, 0, 0, 0);
        aR1 = __builtin_amdgcn_mfma_f32_16x16x32_bf16(ah.v, blR1, aR1, 0, 0, 0);
    }
    const int crow = kg * 4;
    #pragma unroll
    for (int r = 0; r < 4; ++r) {
        size_t orow = (size_t)(rb + crow + r);
        xl2[orow * 128 + wc * 32 + row]      = aL0[r];
        xl2[orow * 128 + wc * 32 + 16 + row] = aL1[r];
        xr2[orow * 128 + wc * 32 + row]      = aR0[r];
        xr2[orow * 128 + wc * 32 + 16 + row] = aR1[r];
    }
}

// ---------------- fused GATv2, wave-per-dst, batch-4 edges + lookahead + XCD swizzle ----------------
template<int NH, int CD>
__global__ __launch_bounds__(256) void k_gat(
    const float* __restrict__ xl, const float* __restrict__ xr,
    const float* __restrict__ att, const int* __restrict__ ei,
    const int* __restrict__ rowptr, const int* __restrict__ eids,
    const float* __restrict__ bias, float* __restrict__ out)
{
    const int BD = NH * CD;        // 256 (NH=2) or 128 (NH=1)
    const int NC = BD / 64;        // 4 or 2
    int bs = (blockIdx.x & 7) * 1000 + (blockIdx.x >> 3);   // XCD-contiguous remap
    int wid = bs * 4 + (threadIdx.x >> 6);
    int lane = threadIdx.x & 63;
    if (wid >= G_ * NN_) return;
    int g = wid / NN_, dst = wid % NN_;
    size_t gbase = (size_t)g * NN_;
    int ch0 = lane * NC;

    float xr_[NC], att_[NC], acc[NC];
    {
        const float* xrp = &xr[(gbase + dst) * BD + ch0];
        #pragma unroll
        for (int j = 0; j < NC; ++j) { xr_[j] = xrp[j]; att_[j] = att[ch0 + j]; acc[j] = 0.f; }
    }
    float m = -1e30f, ssum = 0.f;
    int rs = rowptr[dst], re = rowptr[dst + 1];
    int efull = rs + ((re - rs) & ~3);

#define LOADROW(IDX, DSTV) { \
        int eid_ = eids[IDX]; \
        int src_ = eid_ < E0_ ? ei[eid_] : eid_ - E0_; \
        const float* xp_ = &xl[(gbase + src_) * BD + ch0]; \
        if constexpr (NC == 4) { float4 t_ = *(const float4*)xp_; DSTV[0]=t_.x; DSTV[1]=t_.y; DSTV[2]=t_.z; DSTV[3]=t_.w; } \
        else { float2 t_ = *(const float2*)xp_; DSTV[0]=t_.x; DSTV[1]=t_.y; } \
    }

    int i = rs;
    if (i < efull) {
        float n0[NC], n1[NC], n2[NC], n3[NC];
        LOADROW(i + 0, n0); LOADROW(i + 1, n1); LOADROW(i + 2, n2); LOADROW(i + 3, n3);
        while (i < efull) {
            float r0[NC], r1[NC], r2[NC], r3[NC];
            #pragma unroll
            for (int j = 0; j < NC; ++j) { r0[j]=n0[j]; r1[j]=n1[j]; r2[j]=n2[j]; r3[j]=n3[j]; }
            i += 4;
            if (i < efull) {   // lookahead: next group's loads in flight under the math
                LOADROW(i + 0, n0); LOADROW(i + 1, n1); LOADROW(i + 2, n2); LOADROW(i + 3, n3);
            }
            float p0 = 0.f, p1 = 0.f, p2 = 0.f, p3 = 0.f;
            #pragma unroll
            for (int j = 0; j < NC; ++j) {
                float v0 = r0[j] + xr_[j]; v0 = v0 > 0.f ? v0 : 0.2f * v0; p0 = fmaf(v0, att_[j], p0);
                float v1 = r1[j] + xr_[j]; v1 = v1 > 0.f ? v1 : 0.2f * v1; p1 = fmaf(v1, att_[j], p1);
                float v2 = r2[j] + xr_[j]; v2 = v2 > 0.f ? v2 : 0.2f * v2; p2 = fmaf(v2, att_[j], p2);
                float v3 = r3[j] + xr_[j]; v3 = v3 > 0.f ? v3 : 0.2f * v3; p3 = fmaf(v3, att_[j], p3);
            }
            #pragma unroll
            for (int o = (NH == 2 ? 16 : 32); o; o >>= 1) {   // 4 chains interleaved (ILP)
                p0 += __shfl_xor(p0, o);
                p1 += __shfl_xor(p1, o);
                p2 += __shfl_xor(p2, o);
                p3 += __shfl_xor(p3, o);
            }
            float gm = fmaxf(fmaxf(p0, p1), fmaxf(p2, p3));
            float nm = fmaxf(m, gm);
            float fo = __expf(m - nm);
            float e0 = __expf(p0 - nm), e1 = __expf(p1 - nm);
            float e2 = __expf(p2 - nm), e3 = __expf(p3 - nm);
            #pragma unroll
            for (int j = 0; j < NC; ++j)
                acc[j] = acc[j] * fo + e0 * r0[j] + e1 * r1[j] + e2 * r2[j] + e3 * r3[j];
            ssum = ssum * fo + (e0 + e1 + e2 + e3);
            m = nm;
        }
    }
    for (; i < re; ++i) {   // tail (< 4 edges)
        float cu[NC];
        LOADROW(i, cu);
        float p = 0.f;
        #pragma unroll
        for (int j = 0; j < NC; ++j) {
            float v = cu[j] + xr_[j];
            v = v > 0.f ? v : 0.2f * v;
            p = fmaf(v, att_[j], p);
        }
        #pragma unroll
        for (int o = (NH == 2 ? 16 : 32); o; o >>= 1) p += __shfl_xor(p, o);
        float nm = fmaxf(m, p);
        float fo = __expf(m - nm), en = __expf(p - nm);
        #pragma unroll
        for (int j = 0; j < NC; ++j) acc[j] = acc[j] * fo + en * cu[j];
        ssum = ssum * fo + en;
        m = nm;
    }
#undef LOADROW
    float inv = 1.f / (ssum + 1e-16f);
    float* op = &out[(gbase + dst) * BD + ch0];
    #pragma unroll
    for (int j = 0; j < NC; ++j) op[j] = acc[j] * inv + bias[ch0 + j];
}

// ---------------- BatchNorm stats -> fused scale/shift ----------------
template<int C>
__global__ __launch_bounds__(C * 4) void k_bnstats(
    const float* __restrict__ h, const float* __restrict__ gamma, const float* __restrict__ beta,
    float* __restrict__ scale, float* __restrict__ shift)
{
    int g = blockIdx.x;
    int c = threadIdx.x % C, q = threadIdx.x / C;
    __shared__ float ps[4][C], pss[4][C];
    float s = 0.f, ss = 0.f;
    for (int n = q * 125; n < (q + 1) * 125; ++n) {
        float v = h[((size_t)g * NN_ + n) * C + c];
        s += v; ss += v * v;
    }
    ps[q][c] = s; pss[q][c] = ss;
    __syncthreads();
    if (q == 0) {
        #pragma unroll
        for (int qq = 1; qq < 4; ++qq) { s += ps[qq][c]; ss += pss[qq][c]; }
        float m = s * (1.f / NN_);
        float var = ss * (1.f / NN_) - m * m;
        float r = rsqrtf(var + 1e-5f);
        float sc = r * gamma[c];
        scale[g * C + c] = sc;
        shift[g * C + c] = beta[c] - m * sc;
    }
}

// ---------------- BN2 apply + ELU + residual add (vectorized) ----------------
__global__ void k_bn_elu_add4(const float* __restrict__ h2, const float* __restrict__ scale2,
                              const float* __restrict__ shift2, const float* __restrict__ proj,
                              float* __restrict__ hres) {
    int i4 = blockIdx.x * blockDim.x + threadIdx.x;
    if (i4 >= G_ * NN_ * HD_ / 4) return;
    int base = i4 * 4;
    int c = base & 127;
    int g = base / (NN_ * HD_);
    float4 hv = *(const float4*)&h2[base];
    float4 sc = *(const float4*)&scale2[g * 128 + c];
    float4 sh = *(const float4*)&shift2[g * 128 + c];
    float4 pv = *(const float4*)&proj[base];
    float v0 = hv.x * sc.x + sh.x; v0 = (v0 > 0.f ? v0 : expm1f(v0)) + pv.x;
    float v1 = hv.y * sc.y + sh.y; v1 = (v1 > 0.f ? v1 : expm1f(v1)) + pv.y;
    float v2 = hv.z * sc.z + sh.z; v2 = (v2 > 0.f ? v2 : expm1f(v2)) + pv.z;
    float v3 = hv.w * sc.w + sh.w; v3 = (v3 > 0.f ? v3 : expm1f(v3)) + pv.w;
    *(float4*)&hres[base] = make_float4(v0, v1, v2, v3);
}

// ---------------- persistent LSTM: per-wave 4-gate columns, in-register cell, 1 barrier/iter ----------------
// Full kt unroll: all 32 B-loads hoistable (VGPR headroom: 40 used, cap 256).
__global__ __launch_bounds__(1024, 2) void k_lstm_all(
    const float* __restrict__ hres,
    const unsigned short* __restrict__ WB0, const unsigned short* __restrict__ WB1,
    const float* __restrict__ bih0, const float* __restrict__ bhh0,
    const float* __restrict__ bih1, const float* __restrict__ bhh1,
    const float* __restrict__ fcW1, const float* __restrict__ fcb1,
    const float* __restrict__ fcW2, const float* __restrict__ fcb2,
    float* __restrict__ out)
{
    __shared__ bf16x8 h1h[2][256], h1l[2][256], h2h[2][256], h2l[2][256];
    __shared__ bf16x8 xh[2][256], xlo[2][256];
    int tid = threadIdx.x, lane = tid & 63, w = tid >> 6;   // w 0..15
    int grp = w >> 3, w8 = w & 7;                            // grp 0: layer1, 1: layer2
    int row = lane & 15, kg = lane >> 4;
    int col = w8 * 16 + row;                                 // this lane's h column
    int r0 = blockIdx.x * 16;

    if (tid < 512) {
        bf16x8 z = {0,0,0,0,0,0,0,0};
        ((bf16x8*)h1h)[tid] = z; ((bf16x8*)h1l)[tid] = z;
        ((bf16x8*)h2h)[tid] = z; ((bf16x8*)h2l)[tid] = z;
    }

    const float* bihp = grp ? bih1 : bih0;
    const float* bhhp = grp ? bhh1 : bhh0;
    float bb0 = bihp[col]       + bhhp[col];
    float bb1 = bihp[128 + col] + bhhp[128 + col];
    float bb2 = bihp[256 + col] + bhhp[256 + col];
    float bb3 = bihp[384 + col] + bhhp[384 + col];
    const unsigned short* WB = grp ? WB1 : WB0;

    float cr0 = 0.f, cr1 = 0.f, cr2 = 0.f, cr3 = 0.f;        // cell state, rows kg*4+0..3

    {   // stage x(0) into parity 0
        int lr = tid >> 6, hc2 = tid & 63;
        float2 v = *(const float2*)&hres[((size_t)(r0 + lr) * 16 + 0) * 128 + hc2 * 2];
        unsigned short* XH = (unsigned short*)xh[0];
        unsigned short* XL = (unsigned short*)xlo[0];
        int hc = hc2 * 2, fu = (hc >> 3) * 16 + lr, j = hc & 7;
        unsigned short hb = f2bf(v.x);
        XH[fu * 8 + j] = hb; XL[fu * 8 + j] = f2bf(v.x - bf2f(hb));
        hc = hc2 * 2 + 1; fu = (hc >> 3) * 16 + lr; j = hc & 7;
        hb = f2bf(v.y);
        XH[fu * 8 + j] = hb; XL[fu * 8 + j] = f2bf(v.y - bf2f(hb));
    }
    __syncthreads();

    for (int t = 0; t <= TT_; ++t) {
        int pr = t & 1, pw = pr ^ 1;
        bool active = grp ? (t >= 1) : (t < TT_);
        if (active) {
            const bf16x8* Ahh = grp ? h2h[pr] : h1h[pr];
            const bf16x8* Ahl = grp ? h2l[pr] : h1l[pr];
            const bf16x8* Axh = grp ? h1h[pr] : xh[pr];
            const bf16x8* Axl = grp ? h1l[pr] : xlo[pr];
            f32x4 a0 = {0.f,0.f,0.f,0.f}, a1 = {0.f,0.f,0.f,0.f};
            f32x4 a2 = {0.f,0.f,0.f,0.f}, a3 = {0.f,0.f,0.f,0.f};
            #pragma unroll
            for (int kt = 0; kt < 8; ++kt) {
                const bf16x8* Hh = (kt < 4) ? Ahh : Axh;
                const bf16x8* Hl = (kt < 4) ? Ahl : Axl;
                int fu = ((kt & 3) * 4 + kg) * 16 + row;
                bf16x8 ah = Hh[fu];
                bf16x8 al = Hl[fu];
                const unsigned short* ph = WB + ((size_t)(kt * 4 + kg) * 512 + col) * 8;
                bf16x8 b0 = *(const bf16x8*)(ph);           // gate i  (col)
                bf16x8 b1 = *(const bf16x8*)(ph + 1024);    // gate f  (col+128)
                bf16x8 b2 = *(const bf16x8*)(ph + 2048);    // gate g  (col+256)
                bf16x8 b3 = *(const bf16x8*)(ph + 3072);    // gate o  (col+384)
                a0 = __builtin_amdgcn_mfma_f32_16x16x32_bf16(ah, b0, a0, 0, 0, 0);
                a0 = __builtin_amdgcn_mfma_f32_16x16x32_bf16(al, b0, a0, 0, 0, 0);
                a1 = __builtin_amdgcn_mfma_f32_16x16x32_bf16(ah, b1, a1, 0, 0, 0);
                a1 = __builtin_amdgcn_mfma_f32_16x16x32_bf16(al, b1, a1, 0, 0, 0);
                a2 = __builtin_amdgcn_mfma_f32_16x16x32_bf16(ah, b2, a2, 0, 0, 0);
                a2 = __builtin_amdgcn_mfma_f32_16x16x32_bf16(al, b2, a2, 0, 0, 0);
                a3 = __builtin_amdgcn_mfma_f32_16x16x32_bf16(ah, b3, a3, 0, 0, 0);
                a3 = __builtin_amdgcn_mfma_f32_16x16x32_bf16(al, b3, a3, 0, 0, 0);
            }
            // in-register cell update + h fragment write (C/D: row = kg*4+r, col = col)
            unsigned short* HU = (unsigned short*)(grp ? h2h[pw] : h1h[pw]);
            unsigned short* LU = (unsigned short*)(grp ? h2l[pw] : h1l[pw]);
            const int fub = (col >> 3) * 16;
            const int jj = col & 7;
            #pragma unroll
            for (int r = 0; r < 4; ++r) {
                float gi = a0[r] + bb0;
                float gf = a1[r] + bb1;
                float gg = a2[r] + bb2;
                float go = a3[r] + bb3;
                float cold = (r == 0) ? cr0 : (r == 1) ? cr1 : (r == 2) ? cr2 : cr3;
                float cn = fsig(gf) * cold + fsig(gi) * ftanh(gg);
                if (r == 0) cr0 = cn; else if (r == 1) cr1 = cn; else if (r == 2) cr2 = cn; else cr3 = cn;
                float hv = fsig(go) * ftanh(cn);
                int lrow = kg * 4 + r;
                unsigned short hb = f2bf(hv);
                HU[(fub + lrow) * 8 + jj] = hb;
                LU[(fub + lrow) * 8 + jj] = f2bf(hv - bf2f(hb));
            }
        }
        if (t + 1 < TT_) {   // stage x(t+1) into parity pw (all 1024 threads)
            int lr = tid >> 6, hc2 = tid & 63;
            float2 v = *(const float2*)&hres[((size_t)(r0 + lr) * 16 + (t + 1)) * 128 + hc2 * 2];
            unsigned short* XH = (unsigned short*)xh[pw];
            unsigned short* XL = (unsigned short*)xlo[pw];
            int hc = hc2 * 2, fu = (hc >> 3) * 16 + lr, j = hc & 7;
            unsigned short hb = f2bf(v.x);
            XH[fu * 8 + j] = hb; XL[fu * 8 + j] = f2bf(v.x - bf2f(hb));
            hc = hc2 * 2 + 1; fu = (hc >> 3) * 16 + lr; j = hc & 7;
            hb = f2bf(v.y);
            XH[fu * 8 + j] = hb; XL[fu * 8 + j] = f2bf(v.y - bf2f(hb));
        }
        __syncthreads();
    }
    // FC head: h2(15) fragments live in parity 1 (written at t=16)
    if (tid < 512) {
        const unsigned short* h2hu = (const unsigned short*)h2h[1];
        const unsigned short* h2lu = (const unsigned short*)h2l[1];
        int fr = tid >> 5, j = tid & 31;
        float s0 = fcb1[j], s1 = fcb1[j + 32];
        #pragma unroll 8
        for (int k = 0; k < 128; ++k) {
            int fi = ((k >> 3) * 16 + fr) * 8 + (k & 7);
            float hv = bf2f(h2hu[fi]) + bf2f(h2lu[fi]);
            s0 += hv * fcW1[k * 64 + j];
            s1 += hv * fcW1[k * 64 + j + 32];
        }
        float p = fmaxf(s0, 0.f) * fcW2[j] + fmaxf(s1, 0.f) * fcW2[j + 32];
        #pragma unroll
        for (int o = 16; o; o >>= 1) p += __shfl_xor(p, o);
        if (j == 0) out[r0 + fr] = p + fcb2[0];
    }
}

// ---------------- workspace layout (float offsets) ----------------
static const size_t OFF_XL1  = 0;           // 8,192,000
static const size_t OFF_XR1  = 8192000;     // 8,192,000
static const size_t OFF_H1   = 16384000;    // 8,192,000
static const size_t OFF_XL2  = 24576000;    // 4,096,000
static const size_t OFF_XR2  = 28672000;    // 4,096,000
static const size_t OFF_H2   = 32768000;    // 4,096,000
static const size_t OFF_PRJ  = 36864000;    // 4,096,000
static const size_t OFF_HRES = 40960000;    // 4,096,000
static const size_t OFF_SC1  = 45056000;    // 16384
static const size_t OFF_SH1  = 45072384;    // 16384
static const size_t OFF_SC2  = 45088768;    // 8192
static const size_t OFF_SH2  = 45096960;    // 8192
static const size_t OFF_WT0  = 45105152;    // 131072 floats (hi-only, half used)
static const size_t OFF_WT1  = 45236224;    // 131072 floats
static const size_t OFF_WGP  = 45367296;    // 86016 floats (= 172032 ushorts, 5 gat matrices)
static const size_t OFF_INT  = 45453312;    // int region

extern "C" void kernel_launch(void* const* d_in, const int* in_sizes, int n_in,
                              void* d_out, int out_size, void* d_ws, size_t ws_size,
                              hipStream_t stream) {
    const float* x        = (const float*)d_in[0];
    const int*   ei       = (const int*)  d_in[1];
    const float* W_proj   = (const float*)d_in[2];
    const float* b_proj   = (const float*)d_in[3];
    const float* gat1_Wl  = (const float*)d_in[4];
    const float* gat1_Wr  = (const float*)d_in[5];
    const float* gat1_att = (const float*)d_in[6];
    const float* gat1_b   = (const float*)d_in[7];
    const float* bn1_g    = (const float*)d_in[8];
    const float* bn1_b    = (const float*)d_in[9];
    const float* gat2_Wl  = (const float*)d_in[10];
    const float* gat2_Wr  = (const float*)d_in[11];
    const float* gat2_att = (const float*)d_in[12];
    const float* gat2_b   = (const float*)d_in[13];
    const float* bn2_g    = (const float*)d_in[14];
    const float* bn2_b    = (const float*)d_in[15];
    const float* Wih0     = (const float*)d_in[16];
    const float* Whh0     = (const float*)d_in[17];
    const float* bih0     = (const float*)d_in[18];
    const float* bhh0     = (const float*)d_in[19];
    const float* Wih1     = (const float*)d_in[20];
    const float* Whh1     = (const float*)d_in[21];
    const float* bih1     = (const float*)d_in[22];
    const float* bhh1     = (const float*)d_in[23];
    const float* fc_W1    = (const float*)d_in[24];
    const float* fc_b1    = (const float*)d_in[25];
    const float* fc_W2    = (const float*)d_in[26];
    const float* fc_b2    = (const float*)d_in[27];
    float* out = (float*)d_out;

    float* ws = (float*)d_ws;
    float* xl1  = ws + OFF_XL1;
    float* xr1  = ws + OFF_XR1;
    float* h1   = ws + OFF_H1;
    float* xl2  = ws + OFF_XL2;
    float* xr2  = ws + OFF_XR2;
    float* h2   = ws + OFF_H2;
    float* proj = ws + OFF_PRJ;
    float* hres = ws + OFF_HRES;
    float* sc1  = ws + OFF_SC1;
    float* sh1  = ws + OFF_SH1;
    float* sc2  = ws + OFF_SC2;
    float* sh2  = ws + OFF_SH2;
    unsigned short* WB0 = (unsigned short*)(ws + OFF_WT0);
    unsigned short* WB1 = (unsigned short*)(ws + OFF_WT1);
    unsigned short* WGP = (unsigned short*)(ws + OFF_WGP);

    int* ibase  = (int*)(ws + OFF_INT);
    int* rowptr = ibase;
    int* cursor = ibase + 512;
    int* eids   = ibase + 1024;

    // ---- CSR build + weight prepacks ----
    k_degscan<<<1, 512, 0, stream>>>(ei, rowptr, cursor);
    k_fill<<<(EP_ + 255) / 256, 256, 0, stream>>>(ei, cursor, eids);
    k_wt<<<dim3(512, 2), 256, 0, stream>>>(Whh0, Wih0, Whh1, Wih1, WB0, WB1);
    k_wtg<<<336, 256, 0, stream>>>(gat1_Wl, gat1_Wr, W_proj, gat2_Wl, gat2_Wr, WGP);

    // ---- GAT1 (MFMA GEMM) ----
    k_mm1<<<500, 256, 0, stream>>>(x, WGP, b_proj, xl1, xr1, proj);
    k_gat<2, HD_><<<8000, 256, 0, stream>>>(xl1, xr1, gat1_att, ei, rowptr, eids, gat1_b, h1);
    k_bnstats<C1_><<<G_, C1_ * 4, 0, stream>>>(h1, bn1_g, bn1_b, sc1, sh1);

    // ---- GAT2 (MFMA GEMM, bn1+elu fused on A) ----
    k_mm2<<<1000, 512, 0, stream>>>(h1, WGP, sc1, sh1, xl2, xr2);
    k_gat<1, HD_><<<8000, 256, 0, stream>>>(xl2, xr2, gat2_att, ei, rowptr, eids, gat2_b, h2);
    k_bnstats<HD_><<<G_, HD_ * 4, 0, stream>>>(h2, bn2_g, bn2_b, sc2, sh2);

    // ---- BN2 + ELU + residual ----
    k_bn_elu_add4<<<(G_ * NN_ * HD_ / 4 + 255) / 256, 256, 0, stream>>>(h2, sc2, sh2, proj, hres);

    // ---- persistent LSTM (in-register cell, full-unroll gates) + FC head ----
    k_lstm_all<<<125, 1024, 0, stream>>>(hres, WB0, WB1, bih0, bhh0, bih1, bhh1,
                                         fc_W1, fc_b1, fc_W2, fc_b2, out);
}

// Round 22
// 335.923 us; speedup vs baseline: 1.0524x; 1.0524x over previous
//
#include <hip/hip_runtime.h>
#include <hip/hip_bf16.h>
#include <math.h>

#define G_   64      // B*T graphs
#define NN_  500     // nodes
#define FIN_ 32
#define HD_  128
#define C1_  256     // HEADS*HD
#define E0_  8000
#define EP_  8500    // E0 + self loops
#define TT_  16
#define NR_  2000    // B*N lstm rows

typedef __attribute__((ext_vector_type(8))) short bf16x8;
typedef __attribute__((ext_vector_type(4))) float f32x4;

__device__ __forceinline__ float fsig(float x)  { return 1.f / (1.f + __expf(-x)); }
__device__ __forceinline__ float ftanh(float x) {
    float e = __expf(fminf(fmaxf(2.f * x, -30.f), 30.f));
    return (e - 1.f) / (e + 1.f);
}
__device__ __forceinline__ unsigned short f2bf(float f) {
    unsigned int u = __float_as_uint(f);
    return (unsigned short)((u + 0x7FFFu + ((u >> 16) & 1u)) >> 16);
}
__device__ __forceinline__ float bf2f(unsigned short h) {
    return __uint_as_float(((unsigned int)h) << 16);
}

// ---------------- CSR build (by dst): fused degree+scan, then fill ----------------
__global__ __launch_bounds__(512) void k_degscan(const int* __restrict__ ei,
                                                 int* __restrict__ rowptr, int* __restrict__ cursor) {
    __shared__ int degs[512];
    __shared__ int scan[512];
    int t = threadIdx.x;
    degs[t] = 0;
    __syncthreads();
    for (int e = t; e < EP_; e += 512) {
        int dst = e < E0_ ? ei[E0_ + e] : e - E0_;
        atomicAdd(&degs[dst], 1);
    }
    __syncthreads();
    int v = degs[t];
    scan[t] = v;
    __syncthreads();
    for (int off = 1; off < 512; off <<= 1) {
        int add = (t >= off) ? scan[t - off] : 0;
        __syncthreads();
        scan[t] += add;
        __syncthreads();
    }
    int ex = scan[t] - v;   // exclusive prefix
    if (t < NN_) { rowptr[t] = ex; cursor[t] = ex; }
    if (t == NN_) rowptr[NN_] = ex;
}
__global__ void k_fill(const int* __restrict__ ei, int* __restrict__ cursor, int* __restrict__ eids) {
    int e = blockIdx.x * blockDim.x + threadIdx.x;
    if (e >= EP_) return;
    int dst = e < E0_ ? ei[E0_ + e] : e - E0_;
    int pos = atomicAdd(&cursor[dst], 1);
    eids[pos] = e;
}

// ---------------- LSTM weight prepack: bf16-hi only ----------------
__global__ void k_wt(const float* __restrict__ Whh0, const float* __restrict__ Wih0,
                     const float* __restrict__ Whh1, const float* __restrict__ Wih1,
                     unsigned short* __restrict__ WB0, unsigned short* __restrict__ WB1) {
    int layer = blockIdx.y;
    int n = blockIdx.x * 256 + threadIdx.x;   // 0..131071
    const float* Wh = layer ? Whh1 : Whh0;
    const float* Wi = layer ? Wih1 : Wih0;
    unsigned short* WB = layer ? WB1 : WB0;
    int j = n & 7, col = (n >> 3) & 511, kb8 = n >> 12;
    int k = kb8 * 8 + j;
    float w = (k < 128) ? Wh[(size_t)col * 128 + k] : Wi[(size_t)col * 128 + (k - 128)];
    WB[n] = f2bf(w);
}

// ---------------- GAT weight prepack: 5 matrices -> hi/lo B-fragments ----------------
__global__ void k_wtg(const float* __restrict__ Wl1, const float* __restrict__ Wr1,
                      const float* __restrict__ Wp,  const float* __restrict__ W2l,
                      const float* __restrict__ W2r, unsigned short* __restrict__ out) {
    int t = blockIdx.x * 256 + threadIdx.x;
    if (t >= 86016) return;
    const float* W; int N, base, local, KN;
    if (t < 8192)       { W = Wl1; N = 256; base = 0;      local = t;         KN = 8192;  }
    else if (t < 16384) { W = Wr1; N = 256; base = 16384;  local = t - 8192;  KN = 8192;  }
    else if (t < 20480) { W = Wp;  N = 128; base = 32768;  local = t - 16384; KN = 4096;  }
    else if (t < 53248) { W = W2l; N = 128; base = 40960;  local = t - 20480; KN = 32768; }
    else                { W = W2r; N = 128; base = 106496; local = t - 53248; KN = 32768; }
    int k = local / N, n = local - k * N;
    float wv = W[local];
    int idx = ((k >> 3) * N + n) * 8 + (k & 7);
    unsigned short h = f2bf(wv);
    out[base + idx] = h;
    out[base + KN + idx] = f2bf(wv - bf2f(h));
}

// ---------------- MFMA GEMM 1: x[32000,32] @ {Wl,Wr,Wp} -> xl1, xr1, proj ----------------
__global__ __launch_bounds__(256) void k_mm1(
    const float* __restrict__ x, const unsigned short* __restrict__ WP,
    const float* __restrict__ bp,
    float* __restrict__ xl1, float* __restrict__ xr1, float* __restrict__ proj)
{
    int tid = threadIdx.x, lane = tid & 63, w = tid >> 6;
    int row = lane & 15, kg = lane >> 4;
    int rb = blockIdx.x * 64 + w * 16;
    const float* ap = &x[(size_t)(rb + row) * 32 + kg * 8];
    float4 a0 = *(const float4*)ap, a1 = *(const float4*)(ap + 4);
    union { unsigned short u[8]; bf16x8 v; } ah, al;
    {
        float av[8] = {a0.x,a0.y,a0.z,a0.w,a1.x,a1.y,a1.z,a1.w};
        #pragma unroll
        for (int j = 0; j < 8; ++j) {
            unsigned short hb = f2bf(av[j]);
            ah.u[j] = hb;
            al.u[j] = f2bf(av[j] - bf2f(hb));
        }
    }
    const int crow = kg * 4;
    #pragma unroll 4
    for (int nt = 0; nt < 16; ++nt) {
        int n = nt * 16 + row;
        int idx = (kg * 256 + n) * 8;
        bf16x8 bh = *(const bf16x8*)(WP + idx);
        bf16x8 bl = *(const bf16x8*)(WP + 8192 + idx);
        f32x4 acc = {0.f,0.f,0.f,0.f};
        acc = __builtin_amdgcn_mfma_f32_16x16x32_bf16(ah.v, bh, acc, 0, 0, 0);
        acc = __builtin_amdgcn_mfma_f32_16x16x32_bf16(al.v, bh, acc, 0, 0, 0);
        acc = __builtin_amdgcn_mfma_f32_16x16x32_bf16(ah.v, bl, acc, 0, 0, 0);
        #pragma unroll
        for (int r = 0; r < 4; ++r)
            xl1[(size_t)(rb + crow + r) * 256 + n] = acc[r];
    }
    #pragma unroll 4
    for (int nt = 0; nt < 16; ++nt) {
        int n = nt * 16 + row;
        int idx = (kg * 256 + n) * 8;
        bf16x8 bh = *(const bf16x8*)(WP + 16384 + idx);
        bf16x8 bl = *(const bf16x8*)(WP + 24576 + idx);
        f32x4 acc = {0.f,0.f,0.f,0.f};
        acc = __builtin_amdgcn_mfma_f32_16x16x32_bf16(ah.v, bh, acc, 0, 0, 0);
        acc = __builtin_amdgcn_mfma_f32_16x16x32_bf16(al.v, bh, acc, 0, 0, 0);
        acc = __builtin_amdgcn_mfma_f32_16x16x32_bf16(ah.v, bl, acc, 0, 0, 0);
        #pragma unroll
        for (int r = 0; r < 4; ++r)
            xr1[(size_t)(rb + crow + r) * 256 + n] = acc[r];
    }
    #pragma unroll 4
    for (int nt = 0; nt < 8; ++nt) {
        int n = nt * 16 + row;
        int idx = (kg * 128 + n) * 8;
        bf16x8 bh = *(const bf16x8*)(WP + 32768 + idx);
        bf16x8 bl = *(const bf16x8*)(WP + 36864 + idx);
        f32x4 acc = {0.f,0.f,0.f,0.f};
        acc = __builtin_amdgcn_mfma_f32_16x16x32_bf16(ah.v, bh, acc, 0, 0, 0);
        acc = __builtin_amdgcn_mfma_f32_16x16x32_bf16(al.v, bh, acc, 0, 0, 0);
        acc = __builtin_amdgcn_mfma_f32_16x16x32_bf16(ah.v, bl, acc, 0, 0, 0);
        float bv = bp[n];
        #pragma unroll
        for (int r = 0; r < 4; ++r)
            proj[(size_t)(rb + crow + r) * 128 + n] = acc[r] + bv;
    }
}

// ---------------- MFMA GEMM 2: elu(bn(h1)) @ {W2l,W2r} -> xl2, xr2 ----------------
__global__ __launch_bounds__(512) void k_mm2(
    const float* __restrict__ h1, const unsigned short* __restrict__ WP,
    const float* __restrict__ sc1, const float* __restrict__ sh1,
    float* __restrict__ xl2, float* __restrict__ xr2)
{
    int tid = threadIdx.x, lane = tid & 63, w = tid >> 6;
    int wr = w >> 2, wc = w & 3;
    int row = lane & 15, kg = lane >> 4;
    int rb = blockIdx.x * 32 + wr * 16;
    int grow = rb + row;
    int g = grow / NN_;
    const float* scp = sc1 + g * 256;
    const float* shp = sh1 + g * 256;
    const int cb = wc * 32 + row;
    f32x4 aL0 = {0.f,0.f,0.f,0.f}, aL1 = {0.f,0.f,0.f,0.f};
    f32x4 aR0 = {0.f,0.f,0.f,0.f}, aR1 = {0.f,0.f,0.f,0.f};
    #pragma unroll 2
    for (int kt = 0; kt < 8; ++kt) {
        int k0 = kt * 32 + kg * 8;
        const float* hp = &h1[(size_t)grow * 256 + k0];
        float4 h0 = *(const float4*)hp, h4 = *(const float4*)(hp + 4);
        float4 s0 = *(const float4*)&scp[k0], s4 = *(const float4*)&scp[k0 + 4];
        float4 t0 = *(const float4*)&shp[k0], t4 = *(const float4*)&shp[k0 + 4];
        union { unsigned short u[8]; bf16x8 v; } ah, al;
        {
            float hv[8] = {h0.x,h0.y,h0.z,h0.w,h4.x,h4.y,h4.z,h4.w};
            float sv[8] = {s0.x,s0.y,s0.z,s0.w,s4.x,s4.y,s4.z,s4.w};
            float tv[8] = {t0.x,t0.y,t0.z,t0.w,t4.x,t4.y,t4.z,t4.w};
            #pragma unroll
            for (int j = 0; j < 8; ++j) {
                float v = hv[j] * sv[j] + tv[j];
                v = v > 0.f ? v : expm1f(v);
                unsigned short hb = f2bf(v);
                ah.u[j] = hb;
                al.u[j] = f2bf(v - bf2f(hb));
            }
        }
        int idx = ((kt * 4 + kg) * 128 + cb) * 8;
        bf16x8 bhL0 = *(const bf16x8*)(WP + 40960 + idx);
        bf16x8 blL0 = *(const bf16x8*)(WP + 73728 + idx);
        bf16x8 bhL1 = *(const bf16x8*)(WP + 40960 + idx + 128);
        bf16x8 blL1 = *(const bf16x8*)(WP + 73728 + idx + 128);
        bf16x8 bhR0 = *(const bf16x8*)(WP + 106496 + idx);
        bf16x8 blR0 = *(const bf16x8*)(WP + 139264 + idx);
        bf16x8 bhR1 = *(const bf16x8*)(WP + 106496 + idx + 128);
        bf16x8 blR1 = *(const bf16x8*)(WP + 139264 + idx + 128);
        aL0 = __builtin_amdgcn_mfma_f32_16x16x32_bf16(ah.v, bhL0, aL0, 0, 0, 0);
        aL0 = __builtin_amdgcn_mfma_f32_16x16x32_bf16(al.v, bhL0, aL0, 0, 0, 0);
        aL0 = __builtin_amdgcn_mfma_f32_16x16x32_bf16(ah.v, blL0, aL0, 0, 0, 0);
        aL1 = __builtin_amdgcn_mfma_f32_16x16x32_bf16(ah.v, bhL1, aL1, 0, 0, 0);
        aL1 = __builtin_amdgcn_mfma_f32_16x16x32_bf16(al.v, bhL1, aL1, 0, 0, 0);
        aL1 = __builtin_amdgcn_mfma_f32_16x16x32_bf16(ah.v, blL1, aL1, 0, 0, 0);
        aR0 = __builtin_amdgcn_mfma_f32_16x16x32_bf16(ah.v, bhR0, aR0, 0, 0, 0);
        aR0 = __builtin_amdgcn_mfma_f32_16x16x32_bf16(al.v, bhR0, aR0, 0, 0, 0);
        aR0 = __builtin_amdgcn_mfma_f32_16x16x32_bf16(ah.v, blR0, aR0, 0, 0, 0);
        aR1 = __builtin_amdgcn_mfma_f32_16x16x32_bf16(ah.v, bhR1, aR1, 0, 0, 0);
        aR1 = __builtin_amdgcn_mfma_f32_16x16x32_bf16(al.v, bhR1, aR1, 0, 0, 0);
        aR1 = __builtin_amdgcn_mfma_f32_16x16x32_bf16(ah.v, blR1, aR1, 0, 0, 0);
    }
    const int crow = kg * 4;
    #pragma unroll
    for (int r = 0; r < 4; ++r) {
        size_t orow = (size_t)(rb + crow + r);
        xl2[orow * 128 + wc * 32 + row]      = aL0[r];
        xl2[orow * 128 + wc * 32 + 16 + row] = aL1[r];
        xr2[orow * 128 + wc * 32 + row]      = aR0[r];
        xr2[orow * 128 + wc * 32 + 16 + row] = aR1[r];
    }
}

// ---------------- fused GATv2, wave-per-dst, batch-4 edges + lookahead + XCD swizzle ----------------
template<int NH, int CD>
__global__ __launch_bounds__(256) void k_gat(
    const float* __restrict__ xl, const float* __restrict__ xr,
    const float* __restrict__ att, const int* __restrict__ ei,
    const int* __restrict__ rowptr, const int* __restrict__ eids,
    const float* __restrict__ bias, float* __restrict__ out)
{
    const int BD = NH * CD;        // 256 (NH=2) or 128 (NH=1)
    const int NC = BD / 64;        // 4 or 2
    int bs = (blockIdx.x & 7) * 1000 + (blockIdx.x >> 3);   // XCD-contiguous remap
    int wid = bs * 4 + (threadIdx.x >> 6);
    int lane = threadIdx.x & 63;
    if (wid >= G_ * NN_) return;
    int g = wid / NN_, dst = wid % NN_;
    size_t gbase = (size_t)g * NN_;
    int ch0 = lane * NC;

    float xr_[NC], att_[NC], acc[NC];
    {
        const float* xrp = &xr[(gbase + dst) * BD + ch0];
        #pragma unroll
        for (int j = 0; j < NC; ++j) { xr_[j] = xrp[j]; att_[j] = att[ch0 + j]; acc[j] = 0.f; }
    }
    float m = -1e30f, ssum = 0.f;
    int rs = rowptr[dst], re = rowptr[dst + 1];
    int efull = rs + ((re - rs) & ~3);

#define LOADROW(IDX, DSTV) { \
        int eid_ = eids[IDX]; \
        int src_ = eid_ < E0_ ? ei[eid_] : eid_ - E0_; \
        const float* xp_ = &xl[(gbase + src_) * BD + ch0]; \
        if constexpr (NC == 4) { float4 t_ = *(const float4*)xp_; DSTV[0]=t_.x; DSTV[1]=t_.y; DSTV[2]=t_.z; DSTV[3]=t_.w; } \
        else { float2 t_ = *(const float2*)xp_; DSTV[0]=t_.x; DSTV[1]=t_.y; } \
    }

    int i = rs;
    if (i < efull) {
        float n0[NC], n1[NC], n2[NC], n3[NC];
        LOADROW(i + 0, n0); LOADROW(i + 1, n1); LOADROW(i + 2, n2); LOADROW(i + 3, n3);
        while (i < efull) {
            float r0[NC], r1[NC], r2[NC], r3[NC];
            #pragma unroll
            for (int j = 0; j < NC; ++j) { r0[j]=n0[j]; r1[j]=n1[j]; r2[j]=n2[j]; r3[j]=n3[j]; }
            i += 4;
            if (i < efull) {   // lookahead: next group's loads in flight under the math
                LOADROW(i + 0, n0); LOADROW(i + 1, n1); LOADROW(i + 2, n2); LOADROW(i + 3, n3);
            }
            float p0 = 0.f, p1 = 0.f, p2 = 0.f, p3 = 0.f;
            #pragma unroll
            for (int j = 0; j < NC; ++j) {
                float v0 = r0[j] + xr_[j]; v0 = v0 > 0.f ? v0 : 0.2f * v0; p0 = fmaf(v0, att_[j], p0);
                float v1 = r1[j] + xr_[j]; v1 = v1 > 0.f ? v1 : 0.2f * v1; p1 = fmaf(v1, att_[j], p1);
                float v2 = r2[j] + xr_[j]; v2 = v2 > 0.f ? v2 : 0.2f * v2; p2 = fmaf(v2, att_[j], p2);
                float v3 = r3[j] + xr_[j]; v3 = v3 > 0.f ? v3 : 0.2f * v3; p3 = fmaf(v3, att_[j], p3);
            }
            #pragma unroll
            for (int o = (NH == 2 ? 16 : 32); o; o >>= 1) {   // 4 chains interleaved (ILP)
                p0 += __shfl_xor(p0, o);
                p1 += __shfl_xor(p1, o);
                p2 += __shfl_xor(p2, o);
                p3 += __shfl_xor(p3, o);
            }
            float gm = fmaxf(fmaxf(p0, p1), fmaxf(p2, p3));
            float nm = fmaxf(m, gm);
            float fo = __expf(m - nm);
            float e0 = __expf(p0 - nm), e1 = __expf(p1 - nm);
            float e2 = __expf(p2 - nm), e3 = __expf(p3 - nm);
            #pragma unroll
            for (int j = 0; j < NC; ++j)
                acc[j] = acc[j] * fo + e0 * r0[j] + e1 * r1[j] + e2 * r2[j] + e3 * r3[j];
            ssum = ssum * fo + (e0 + e1 + e2 + e3);
            m = nm;
        }
    }
    for (; i < re; ++i) {   // tail (< 4 edges)
        float cu[NC];
        LOADROW(i, cu);
        float p = 0.f;
        #pragma unroll
        for (int j = 0; j < NC; ++j) {
            float v = cu[j] + xr_[j];
            v = v > 0.f ? v : 0.2f * v;
            p = fmaf(v, att_[j], p);
        }
        #pragma unroll
        for (int o = (NH == 2 ? 16 : 32); o; o >>= 1) p += __shfl_xor(p, o);
        float nm = fmaxf(m, p);
        float fo = __expf(m - nm), en = __expf(p - nm);
        #pragma unroll
        for (int j = 0; j < NC; ++j) acc[j] = acc[j] * fo + en * cu[j];
        ssum = ssum * fo + en;
        m = nm;
    }
#undef LOADROW
    float inv = 1.f / (ssum + 1e-16f);
    float* op = &out[(gbase + dst) * BD + ch0];
    #pragma unroll
    for (int j = 0; j < NC; ++j) op[j] = acc[j] * inv + bias[ch0 + j];
}

// ---------------- BatchNorm stats -> fused scale/shift ----------------
template<int C>
__global__ __launch_bounds__(C * 4) void k_bnstats(
    const float* __restrict__ h, const float* __restrict__ gamma, const float* __restrict__ beta,
    float* __restrict__ scale, float* __restrict__ shift)
{
    int g = blockIdx.x;
    int c = threadIdx.x % C, q = threadIdx.x / C;
    __shared__ float ps[4][C], pss[4][C];
    float s = 0.f, ss = 0.f;
    for (int n = q * 125; n < (q + 1) * 125; ++n) {
        float v = h[((size_t)g * NN_ + n) * C + c];
        s += v; ss += v * v;
    }
    ps[q][c] = s; pss[q][c] = ss;
    __syncthreads();
    if (q == 0) {
        #pragma unroll
        for (int qq = 1; qq < 4; ++qq) { s += ps[qq][c]; ss += pss[qq][c]; }
        float m = s * (1.f / NN_);
        float var = ss * (1.f / NN_) - m * m;
        float r = rsqrtf(var + 1e-5f);
        float sc = r * gamma[c];
        scale[g * C + c] = sc;
        shift[g * C + c] = beta[c] - m * sc;
    }
}

// ---------------- BN2 apply + ELU + residual add (vectorized) ----------------
__global__ void k_bn_elu_add4(const float* __restrict__ h2, const float* __restrict__ scale2,
                              const float* __restrict__ shift2, const float* __restrict__ proj,
                              float* __restrict__ hres) {
    int i4 = blockIdx.x * blockDim.x + threadIdx.x;
    if (i4 >= G_ * NN_ * HD_ / 4) return;
    int base = i4 * 4;
    int c = base & 127;
    int g = base / (NN_ * HD_);
    float4 hv = *(const float4*)&h2[base];
    float4 sc = *(const float4*)&scale2[g * 128 + c];
    float4 sh = *(const float4*)&shift2[g * 128 + c];
    float4 pv = *(const float4*)&proj[base];
    float v0 = hv.x * sc.x + sh.x; v0 = (v0 > 0.f ? v0 : expm1f(v0)) + pv.x;
    float v1 = hv.y * sc.y + sh.y; v1 = (v1 > 0.f ? v1 : expm1f(v1)) + pv.y;
    float v2 = hv.z * sc.z + sh.z; v2 = (v2 > 0.f ? v2 : expm1f(v2)) + pv.z;
    float v3 = hv.w * sc.w + sh.w; v3 = (v3 > 0.f ? v3 : expm1f(v3)) + pv.w;
    *(float4*)&hres[base] = make_float4(v0, v1, v2, v3);
}

// ---------------- persistent LSTM: per-wave 4-gate columns, in-register cell, 1 barrier/iter ----------------
// Wave w8 of group grp owns h-cols [w8*16, w8*16+16) across ALL 4 gates (B-tiles at
// gt*128 + w8*16). After MFMA each lane holds i,f,g,o for its (row,col) pairs -> cell
// update fully in registers (c-state in 4 VGPRs), h written to LDS in A-frag layout.
// h1/h2/x parity double-buffered: iter t reads buf[t&1], writes buf[t&1^1] -> ONE barrier.
__global__ __launch_bounds__(1024, 2) void k_lstm_all(
    const float* __restrict__ hres,
    const unsigned short* __restrict__ WB0, const unsigned short* __restrict__ WB1,
    const float* __restrict__ bih0, const float* __restrict__ bhh0,
    const float* __restrict__ bih1, const float* __restrict__ bhh1,
    const float* __restrict__ fcW1, const float* __restrict__ fcb1,
    const float* __restrict__ fcW2, const float* __restrict__ fcb2,
    float* __restrict__ out)
{
    __shared__ bf16x8 h1h[2][256], h1l[2][256], h2h[2][256], h2l[2][256];
    __shared__ bf16x8 xh[2][256], xlo[2][256];
    int tid = threadIdx.x, lane = tid & 63, w = tid >> 6;   // w 0..15
    int grp = w >> 3, w8 = w & 7;                            // grp 0: layer1, 1: layer2
    int row = lane & 15, kg = lane >> 4;
    int col = w8 * 16 + row;                                 // this lane's h column
    int r0 = blockIdx.x * 16;

    if (tid < 512) {
        bf16x8 z = {0,0,0,0,0,0,0,0};
        ((bf16x8*)h1h)[tid] = z; ((bf16x8*)h1l)[tid] = z;
        ((bf16x8*)h2h)[tid] = z; ((bf16x8*)h2l)[tid] = z;
    }

    const float* bihp = grp ? bih1 : bih0;
    const float* bhhp = grp ? bhh1 : bhh0;
    float bb0 = bihp[col]       + bhhp[col];
    float bb1 = bihp[128 + col] + bhhp[128 + col];
    float bb2 = bihp[256 + col] + bhhp[256 + col];
    float bb3 = bihp[384 + col] + bhhp[384 + col];
    const unsigned short* WB = grp ? WB1 : WB0;

    float cr0 = 0.f, cr1 = 0.f, cr2 = 0.f, cr3 = 0.f;        // cell state, rows kg*4+0..3

    {   // stage x(0) into parity 0
        int lr = tid >> 6, hc2 = tid & 63;
        float2 v = *(const float2*)&hres[((size_t)(r0 + lr) * 16 + 0) * 128 + hc2 * 2];
        unsigned short* XH = (unsigned short*)xh[0];
        unsigned short* XL = (unsigned short*)xlo[0];
        int hc = hc2 * 2, fu = (hc >> 3) * 16 + lr, j = hc & 7;
        unsigned short hb = f2bf(v.x);
        XH[fu * 8 + j] = hb; XL[fu * 8 + j] = f2bf(v.x - bf2f(hb));
        hc = hc2 * 2 + 1; fu = (hc >> 3) * 16 + lr; j = hc & 7;
        hb = f2bf(v.y);
        XH[fu * 8 + j] = hb; XL[fu * 8 + j] = f2bf(v.y - bf2f(hb));
    }
    __syncthreads();

    for (int t = 0; t <= TT_; ++t) {
        int pr = t & 1, pw = pr ^ 1;
        bool active = grp ? (t >= 1) : (t < TT_);
        if (active) {
            const bf16x8* Ahh = grp ? h2h[pr] : h1h[pr];
            const bf16x8* Ahl = grp ? h2l[pr] : h1l[pr];
            const bf16x8* Axh = grp ? h1h[pr] : xh[pr];
            const bf16x8* Axl = grp ? h1l[pr] : xlo[pr];
            f32x4 a0 = {0.f,0.f,0.f,0.f}, a1 = {0.f,0.f,0.f,0.f};
            f32x4 a2 = {0.f,0.f,0.f,0.f}, a3 = {0.f,0.f,0.f,0.f};
            #pragma unroll 4
            for (int kt = 0; kt < 8; ++kt) {
                const bf16x8* Hh = (kt < 4) ? Ahh : Axh;
                const bf16x8* Hl = (kt < 4) ? Ahl : Axl;
                int fu = ((kt & 3) * 4 + kg) * 16 + row;
                bf16x8 ah = Hh[fu];
                bf16x8 al = Hl[fu];
                const unsigned short* ph = WB + ((size_t)(kt * 4 + kg) * 512 + col) * 8;
                bf16x8 b0 = *(const bf16x8*)(ph);           // gate i  (col)
                bf16x8 b1 = *(const bf16x8*)(ph + 1024);    // gate f  (col+128)
                bf16x8 b2 = *(const bf16x8*)(ph + 2048);    // gate g  (col+256)
                bf16x8 b3 = *(const bf16x8*)(ph + 3072);    // gate o  (col+384)
                a0 = __builtin_amdgcn_mfma_f32_16x16x32_bf16(ah, b0, a0, 0, 0, 0);
                a0 = __builtin_amdgcn_mfma_f32_16x16x32_bf16(al, b0, a0, 0, 0, 0);
                a1 = __builtin_amdgcn_mfma_f32_16x16x32_bf16(ah, b1, a1, 0, 0, 0);
                a1 = __builtin_amdgcn_mfma_f32_16x16x32_bf16(al, b1, a1, 0, 0, 0);
                a2 = __builtin_amdgcn_mfma_f32_16x16x32_bf16(ah, b2, a2, 0, 0, 0);
                a2 = __builtin_amdgcn_mfma_f32_16x16x32_bf16(al, b2, a2, 0, 0, 0);
                a3 = __builtin_amdgcn_mfma_f32_16x16x32_bf16(ah, b3, a3, 0, 0, 0);
                a3 = __builtin_amdgcn_mfma_f32_16x16x32_bf16(al, b3, a3, 0, 0, 0);
            }
            // in-register cell update + h fragment write (C/D: row = kg*4+r, col = col)
            unsigned short* HU = (unsigned short*)(grp ? h2h[pw] : h1h[pw]);
            unsigned short* LU = (unsigned short*)(grp ? h2l[pw] : h1l[pw]);
            const int fub = (col >> 3) * 16;
            const int jj = col & 7;
            #pragma unroll
            for (int r = 0; r < 4; ++r) {
                float gi = a0[r] + bb0;
                float gf = a1[r] + bb1;
                float gg = a2[r] + bb2;
                float go = a3[r] + bb3;
                float cold = (r == 0) ? cr0 : (r == 1) ? cr1 : (r == 2) ? cr2 : cr3;
                float cn = fsig(gf) * cold + fsig(gi) * ftanh(gg);
                if (r == 0) cr0 = cn; else if (r == 1) cr1 = cn; else if (r == 2) cr2 = cn; else cr3 = cn;
                float hv = fsig(go) * ftanh(cn);
                int lrow = kg * 4 + r;
                unsigned short hb = f2bf(hv);
                HU[(fub + lrow) * 8 + jj] = hb;
                LU[(fub + lrow) * 8 + jj] = f2bf(hv - bf2f(hb));
            }
        }
        if (t + 1 < TT_) {   // stage x(t+1) into parity pw (all 1024 threads)
            int lr = tid >> 6, hc2 = tid & 63;
            float2 v = *(const float2*)&hres[((size_t)(r0 + lr) * 16 + (t + 1)) * 128 + hc2 * 2];
            unsigned short* XH = (unsigned short*)xh[pw];
            unsigned short* XL = (unsigned short*)xlo[pw];
            int hc = hc2 * 2, fu = (hc >> 3) * 16 + lr, j = hc & 7;
            unsigned short hb = f2bf(v.x);
            XH[fu * 8 + j] = hb; XL[fu * 8 + j] = f2bf(v.x - bf2f(hb));
            hc = hc2 * 2 + 1; fu = (hc >> 3) * 16 + lr; j = hc & 7;
            hb = f2bf(v.y);
            XH[fu * 8 + j] = hb; XL[fu * 8 + j] = f2bf(v.y - bf2f(hb));
        }
        __syncthreads();
    }
    // FC head: h2(15) fragments live in parity 1 (written at t=16)
    if (tid < 512) {
        const unsigned short* h2hu = (const unsigned short*)h2h[1];
        const unsigned short* h2lu = (const unsigned short*)h2l[1];
        int fr = tid >> 5, j = tid & 31;
        float s0 = fcb1[j], s1 = fcb1[j + 32];
        #pragma unroll 8
        for (int k = 0; k < 128; ++k) {
            int fi = ((k >> 3) * 16 + fr) * 8 + (k & 7);
            float hv = bf2f(h2hu[fi]) + bf2f(h2lu[fi]);
            s0 += hv * fcW1[k * 64 + j];
            s1 += hv * fcW1[k * 64 + j + 32];
        }
        float p = fmaxf(s0, 0.f) * fcW2[j] + fmaxf(s1, 0.f) * fcW2[j + 32];
        #pragma unroll
        for (int o = 16; o; o >>= 1) p += __shfl_xor(p, o);
        if (j == 0) out[r0 + fr] = p + fcb2[0];
    }
}

// ---------------- workspace layout (float offsets) ----------------
static const size_t OFF_XL1  = 0;           // 8,192,000
static const size_t OFF_XR1  = 8192000;     // 8,192,000
static const size_t OFF_H1   = 16384000;    // 8,192,000
static const size_t OFF_XL2  = 24576000;    // 4,096,000
static const size_t OFF_XR2  = 28672000;    // 4,096,000
static const size_t OFF_H2   = 32768000;    // 4,096,000
static const size_t OFF_PRJ  = 36864000;    // 4,096,000
static const size_t OFF_HRES = 40960000;    // 4,096,000
static const size_t OFF_SC1  = 45056000;    // 16384
static const size_t OFF_SH1  = 45072384;    // 16384
static const size_t OFF_SC2  = 45088768;    // 8192
static const size_t OFF_SH2  = 45096960;    // 8192
static const size_t OFF_WT0  = 45105152;    // 131072 floats (hi-only, half used)
static const size_t OFF_WT1  = 45236224;    // 131072 floats
static const size_t OFF_WGP  = 45367296;    // 86016 floats (= 172032 ushorts, 5 gat matrices)
static const size_t OFF_INT  = 45453312;    // int region

extern "C" void kernel_launch(void* const* d_in, const int* in_sizes, int n_in,
                              void* d_out, int out_size, void* d_ws, size_t ws_size,
                              hipStream_t stream) {
    const float* x        = (const float*)d_in[0];
    const int*   ei       = (const int*)  d_in[1];
    const float* W_proj   = (const float*)d_in[2];
    const float* b_proj   = (const float*)d_in[3];
    const float* gat1_Wl  = (const float*)d_in[4];
    const float* gat1_Wr  = (const float*)d_in[5];
    const float* gat1_att = (const float*)d_in[6];
    const float* gat1_b   = (const float*)d_in[7];
    const float* bn1_g    = (const float*)d_in[8];
    const float* bn1_b    = (const float*)d_in[9];
    const float* gat2_Wl  = (const float*)d_in[10];
    const float* gat2_Wr  = (const float*)d_in[11];
    const float* gat2_att = (const float*)d_in[12];
    const float* gat2_b   = (const float*)d_in[13];
    const float* bn2_g    = (const float*)d_in[14];
    const float* bn2_b    = (const float*)d_in[15];
    const float* Wih0     = (const float*)d_in[16];
    const float* Whh0     = (const float*)d_in[17];
    const float* bih0     = (const float*)d_in[18];
    const float* bhh0     = (const float*)d_in[19];
    const float* Wih1     = (const float*)d_in[20];
    const float* Whh1     = (const float*)d_in[21];
    const float* bih1     = (const float*)d_in[22];
    const float* bhh1     = (const float*)d_in[23];
    const float* fc_W1    = (const float*)d_in[24];
    const float* fc_b1    = (const float*)d_in[25];
    const float* fc_W2    = (const float*)d_in[26];
    const float* fc_b2    = (const float*)d_in[27];
    float* out = (float*)d_out;

    float* ws = (float*)d_ws;
    float* xl1  = ws + OFF_XL1;
    float* xr1  = ws + OFF_XR1;
    float* h1   = ws + OFF_H1;
    float* xl2  = ws + OFF_XL2;
    float* xr2  = ws + OFF_XR2;
    float* h2   = ws + OFF_H2;
    float* proj = ws + OFF_PRJ;
    float* hres = ws + OFF_HRES;
    float* sc1  = ws + OFF_SC1;
    float* sh1  = ws + OFF_SH1;
    float* sc2  = ws + OFF_SC2;
    float* sh2  = ws + OFF_SH2;
    unsigned short* WB0 = (unsigned short*)(ws + OFF_WT0);
    unsigned short* WB1 = (unsigned short*)(ws + OFF_WT1);
    unsigned short* WGP = (unsigned short*)(ws + OFF_WGP);

    int* ibase  = (int*)(ws + OFF_INT);
    int* rowptr = ibase;
    int* cursor = ibase + 512;
    int* eids   = ibase + 1024;

    // ---- CSR build + weight prepacks ----
    k_degscan<<<1, 512, 0, stream>>>(ei, rowptr, cursor);
    k_fill<<<(EP_ + 255) / 256, 256, 0, stream>>>(ei, cursor, eids);
    k_wt<<<dim3(512, 2), 256, 0, stream>>>(Whh0, Wih0, Whh1, Wih1, WB0, WB1);
    k_wtg<<<336, 256, 0, stream>>>(gat1_Wl, gat1_Wr, W_proj, gat2_Wl, gat2_Wr, WGP);

    // ---- GAT1 (MFMA GEMM) ----
    k_mm1<<<500, 256, 0, stream>>>(x, WGP, b_proj, xl1, xr1, proj);
    k_gat<2, HD_><<<8000, 256, 0, stream>>>(xl1, xr1, gat1_att, ei, rowptr, eids, gat1_b, h1);
    k_bnstats<C1_><<<G_, C1_ * 4, 0, stream>>>(h1, bn1_g, bn1_b, sc1, sh1);

    // ---- GAT2 (MFMA GEMM, bn1+elu fused on A) ----
    k_mm2<<<1000, 512, 0, stream>>>(h1, WGP, sc1, sh1, xl2, xr2);
    k_gat<1, HD_><<<8000, 256, 0, stream>>>(xl2, xr2, gat2_att, ei, rowptr, eids, gat2_b, h2);
    k_bnstats<HD_><<<G_, HD_ * 4, 0, stream>>>(h2, bn2_g, bn2_b, sc2, sh2);

    // ---- BN2 + ELU + residual ----
    k_bn_elu_add4<<<(G_ * NN_ * HD_ / 4 + 255) / 256, 256, 0, stream>>>(h2, sc2, sh2, proj, hres);

    // ---- persistent LSTM (in-register cell, 1 barrier/iter) + FC head ----
    k_lstm_all<<<125, 1024, 0, stream>>>(hres, WB0, WB1, bih0, bhh0, bih1, bhh1,
                                         fc_W1, fc_b1, fc_W2, fc_b2, out);
}